// Round 1
// baseline (788.931 us; speedup 1.0000x reference)
//
#include <hip/hip_runtime.h>
#include <hip/hip_bf16.h>

#define NN 32768
#define EE 524288
#define GG 256
#define PP 128

__device__ __forceinline__ float wave_reduce_sum(float v) {
    #pragma unroll
    for (int m = 1; m < 64; m <<= 1) v += __shfl_xor(v, m, 64);
    return v;
}

// ---------------------------------------------------------------------------
// P1: fold W2/W3/W4/biases into A,B (stored transposed+interleaved) and c.
// ABc[k*128 + o]      = A[o][k] = sum_j W4[o*128+j]    * W3[j*64+k]
// ABc[k*128 + 64 + o] = B[o][k] = sum_j W4[o*128+64+j] * W2[j*64+k]
// ABc[8192 + o]       = c[o]    = b4[o] + sum_j W4[o*128+j]*b3[j] + W4[o*128+64+j]*b2[j]
// ---------------------------------------------------------------------------
__global__ void k_prep(const float* __restrict__ W2, const float* __restrict__ b2,
                       const float* __restrict__ W3, const float* __restrict__ b3,
                       const float* __restrict__ W4, const float* __restrict__ b4,
                       float* __restrict__ ABc) {
    int idx = blockIdx.x * blockDim.x + threadIdx.x;   // 16 blocks * 256 = 4096
    int k = idx >> 6, o = idx & 63;
    float a = 0.f, b = 0.f;
    for (int j = 0; j < 64; ++j) {
        a += W4[o*128 + j]      * W3[j*64 + k];
        b += W4[o*128 + 64 + j] * W2[j*64 + k];
    }
    ABc[k*128 + o]      = a;
    ABc[k*128 + 64 + o] = b;
    if (blockIdx.x == 0 && threadIdx.x < 64) {
        int oo = threadIdx.x;
        float c = b4[oo];
        for (int j = 0; j < 64; ++j)
            c += W4[oo*128 + j] * b3[j] + W4[oo*128 + 64 + j] * b2[j];
        ABc[8192 + oo] = c;
    }
}

// ---------------------------------------------------------------------------
// Init: h = normalize(relu(x @ W1.T + b1)).  One wave per node, lane = out idx.
// ---------------------------------------------------------------------------
__global__ void k_init(const float* __restrict__ x, const float* __restrict__ W1,
                       const float* __restrict__ b1, float* __restrict__ h) {
    int node = (blockIdx.x * blockDim.x + threadIdx.x) >> 6;
    int lane = threadIdx.x & 63;
    if (node >= NN) return;
    float acc = b1[lane];
    #pragma unroll
    for (int j = 0; j < 8; ++j)
        acc += x[node*8 + j] * W1[lane*8 + j];
    acc = fmaxf(acc, 0.f);
    float ss = wave_reduce_sum(acc * acc);
    h[node*64 + lane] = acc / sqrtf(ss);
}

// ---------------------------------------------------------------------------
// Scatter: m[dst] += h[src].  One wave per edge, lane = feature.
// ---------------------------------------------------------------------------
__global__ void k_scatter(const int* __restrict__ src, const int* __restrict__ dst,
                          const float* __restrict__ h, float* __restrict__ m) {
    int lane = threadIdx.x & 63;
    int wid  = (blockIdx.x * blockDim.x + threadIdx.x) >> 6;
    int nw   = (gridDim.x * blockDim.x) >> 6;
    for (int e = wid; e < EE; e += nw) {
        int s = src[e], d = dst[e];
        float v = h[(long)s*64 + lane];
        atomicAdd(&m[(long)d*64 + lane], v);
    }
}

// ---------------------------------------------------------------------------
// Update: h_new = normalize(relu(A@m + B@h + c)).  Wave per node, lane = out idx.
// A,B staged in LDS (transposed/interleaved => conflict-free, ds_read2-able).
// ---------------------------------------------------------------------------
__global__ void __launch_bounds__(256) k_update(const float* __restrict__ ABc,
        const float* __restrict__ m, const float* __restrict__ h,
        float* __restrict__ hn) {
    __shared__ float AB[8192];
    __shared__ float cs[64];
    int tid = threadIdx.x;
    for (int i = tid; i < 8192; i += 256) AB[i] = ABc[i];
    if (tid < 64) cs[tid] = ABc[8192 + tid];
    __syncthreads();
    int lane = tid & 63;
    int wv = tid >> 6;
    int stride = gridDim.x * 4;
    for (int node = blockIdx.x * 4 + wv; node < NN; node += stride) {
        float mv = m[node*64 + lane];
        float hv = h[node*64 + lane];
        float acc = cs[lane];
        #pragma unroll
        for (int k = 0; k < 64; ++k) {
            float mk = __shfl(mv, k, 64);
            float hk = __shfl(hv, k, 64);
            acc += AB[k*128 + lane] * mk + AB[k*128 + 64 + lane] * hk;
        }
        acc = fmaxf(acc, 0.f);
        float ss = wave_reduce_sum(acc * acc);
        hn[node*64 + lane] = acc / sqrtf(ss);
    }
}

// ---------------------------------------------------------------------------
// R1: Tt[g][i*64+o] = sum_j W5[o*4096 + i*64 + j] * last[g][j]
// Each block: 8 graphs x 8 i-values (i-chunk), W5 rows reused across 8 graphs.
// ---------------------------------------------------------------------------
__global__ void k_outerT(const float* __restrict__ h, const float* __restrict__ W5,
                         float* __restrict__ Tt) {
    int gg = blockIdx.x >> 3;      // graph group (0..31), 8 graphs each
    int ic = blockIdx.x & 7;       // i-chunk (0..7), 8 i each
    __shared__ float last8[8][64];
    int tid = threadIdx.x;
    for (int idx = tid; idx < 512; idx += 256) {
        int g8 = idx >> 6, j = idx & 63;
        last8[g8][j] = h[((long)(gg*8 + g8)*128 + 127)*64 + j];
    }
    __syncthreads();
    int o = tid & 63;
    int sub = tid >> 6;            // 0..3
    for (int d = 0; d < 2; ++d) {
        int i = ic*8 + sub*2 + d;
        float acc[8] = {0.f,0.f,0.f,0.f,0.f,0.f,0.f,0.f};
        for (int j = 0; j < 64; ++j) {
            float w = W5[(long)o*4096 + i*64 + j];
            #pragma unroll
            for (int g8 = 0; g8 < 8; ++g8) acc[g8] += w * last8[g8][j];
        }
        #pragma unroll
        for (int g8 = 0; g8 < 8; ++g8)
            Tt[(long)(gg*8 + g8)*4096 + i*64 + o] = acc[g8];
    }
}

// ---------------------------------------------------------------------------
// R2: per (g,p):  y1[o] = b5[o] + sum_i others[i]*T[g][o][i]
//                 hid[q] = relu(bd1[q] + sum_o Wd1[q][o]*y1[o])   (q=0..127)
//                 out = bd2 + sum_q Wd2[q]*hid[q]
// 2 blocks per graph; T and Wd1^T staged in LDS; y1 broadcast via shfl (no
// barriers inside the divergent p-loop).
// ---------------------------------------------------------------------------
__global__ void __launch_bounds__(256) k_readout(const float* __restrict__ h,
        const float* __restrict__ Tt, const float* __restrict__ b5,
        const float* __restrict__ Wd1, const float* __restrict__ bd1,
        const float* __restrict__ Wd2, const float* __restrict__ bd2,
        float* __restrict__ out) {
    int g = blockIdx.x >> 1, half = blockIdx.x & 1;
    __shared__ float T_l[4096];     // [i][o]
    __shared__ float W1t[8192];     // [o][q] = Wd1[q*64+o]
    __shared__ float b5_l[64];
    __shared__ float bd1_l[128];
    __shared__ float wd2_l[128];
    int tid = threadIdx.x;
    for (int idx = tid; idx < 4096; idx += 256) T_l[idx] = Tt[(long)g*4096 + idx];
    for (int idx = tid; idx < 8192; idx += 256) {
        int o = idx >> 7, q = idx & 127;
        W1t[idx] = Wd1[q*64 + o];
    }
    if (tid < 64) b5_l[tid] = b5[tid];
    if (tid < 128) { bd1_l[tid] = bd1[tid]; wd2_l[tid] = Wd2[tid]; }
    __syncthreads();
    int lane = tid & 63, wv = tid >> 6;
    float bd2v = bd2[0];
    for (int p = half*4 + wv; p < 127; p += 8) {
        float hv = h[((long)g*128 + p)*64 + lane];
        float acc = b5_l[lane];
        #pragma unroll
        for (int i = 0; i < 64; ++i)
            acc += __shfl(hv, i, 64) * T_l[i*64 + lane];
        float h1 = bd1_l[lane], h2 = bd1_l[64 + lane];
        #pragma unroll
        for (int o = 0; o < 64; ++o) {
            float yv = __shfl(acc, o, 64);
            h1 += W1t[o*128 + lane]      * yv;
            h2 += W1t[o*128 + 64 + lane] * yv;
        }
        h1 = fmaxf(h1, 0.f);
        h2 = fmaxf(h2, 0.f);
        float part = wd2_l[lane]*h1 + wd2_l[64 + lane]*h2;
        part = wave_reduce_sum(part);
        if (lane == 0) out[g*127 + p] = part + bd2v;
    }
}

extern "C" void kernel_launch(void* const* d_in, const int* in_sizes, int n_in,
                              void* d_out, int out_size, void* d_ws, size_t ws_size,
                              hipStream_t stream) {
    const float* x   = (const float*)d_in[0];
    const int*   ei  = (const int*)d_in[1];   // [2][E] int32
    // d_in[2]=batch, d_in[3]=num_graphs : unused (deterministic layout)
    const float* W1  = (const float*)d_in[4];
    const float* b1  = (const float*)d_in[5];
    const float* W2  = (const float*)d_in[6];
    const float* b2  = (const float*)d_in[7];
    const float* W3  = (const float*)d_in[8];
    const float* b3  = (const float*)d_in[9];
    const float* W4  = (const float*)d_in[10];
    const float* b4  = (const float*)d_in[11];
    const float* W5  = (const float*)d_in[12];
    const float* b5  = (const float*)d_in[13];
    const float* Wd1 = (const float*)d_in[14];
    const float* bd1 = (const float*)d_in[15];
    const float* Wd2 = (const float*)d_in[16];
    const float* bd2 = (const float*)d_in[17];
    float* out = (float*)d_out;

    float* ws  = (float*)d_ws;
    float* h0  = ws;                      // 2M floats
    float* h1b = ws + (1u<<21);           // 2M floats
    float* m   = ws + (2u<<21);           // 2M floats
    float* ABc = ws + (3u<<21);           // 8256 floats
    float* Tt  = ws + (3u<<21) + 8448;    // 1M floats

    const int* src = ei;
    const int* dst = ei + EE;

    k_prep<<<16, 256, 0, stream>>>(W2, b2, W3, b3, W4, b4, ABc);
    k_init<<<NN/4, 256, 0, stream>>>(x, W1, b1, h0);

    float* hc = h0; float* hn = h1b;
    for (int l = 0; l < 3; ++l) {
        hipMemsetAsync(m, 0, (size_t)NN*64*sizeof(float), stream);
        k_scatter<<<4096, 256, 0, stream>>>(src, dst, hc, m);
        k_update<<<1024, 256, 0, stream>>>(ABc, m, hc, hn);
        float* t = hc; hc = hn; hn = t;
    }

    k_outerT<<<256, 256, 0, stream>>>(hc, W5, Tt);
    k_readout<<<512, 256, 0, stream>>>(hc, Tt, b5, Wd1, bd1, Wd2, bd2, out);
}

// Round 2
// 493.774 us; speedup vs baseline: 1.5978x; 1.5978x over previous
//
#include <hip/hip_runtime.h>
#include <hip/hip_bf16.h>

#define NN 32768
#define EE 524288
#define GG 256
#define PP 128

// ---------------------------------------------------------------------------
// k_prep: fold W2/W3/W4/b2/b3/b4 into Wc[kk][o] (kk-major, 128x64) + c[o].
// kk<64:  Wc[kk*64+o] = A[o][kk] = sum_j W4[o*128+j]   * W3[j*64+kk]
// kk>=64: Wc[kk*64+o] = B[o][kk-64] = sum_j W4[o*128+64+j]*W2[j*64+kk-64]
// Wc[8192+o] = c[o] = b4[o] + sum_j W4[o*128+j]*b3[j] + W4[o*128+64+j]*b2[j]
// ---------------------------------------------------------------------------
__global__ void k_prep(const float* __restrict__ W2, const float* __restrict__ b2,
                       const float* __restrict__ W3, const float* __restrict__ b3,
                       const float* __restrict__ W4, const float* __restrict__ b4,
                       float* __restrict__ Wc) {
    int idx = blockIdx.x * blockDim.x + threadIdx.x;  // 32*256 = 8192
    int kk = idx >> 6, o = idx & 63;
    float a = 0.f;
    if (kk < 64) {
        for (int j = 0; j < 64; ++j) a += W4[o*128 + j] * W3[j*64 + kk];
    } else {
        int k2 = kk - 64;
        for (int j = 0; j < 64; ++j) a += W4[o*128 + 64 + j] * W2[j*64 + k2];
    }
    Wc[kk*64 + o] = a;
    if (idx < 64) {
        float c = b4[idx];
        for (int j = 0; j < 64; ++j)
            c += W4[idx*128 + j]*b3[j] + W4[idx*128 + 64 + j]*b2[j];
        Wc[8192 + idx] = c;
    }
}

// ---------------------------------------------------------------------------
// k_init: h = normalize(relu(x @ W1.T + b1)). One wave per node, lane = out.
// ---------------------------------------------------------------------------
__global__ void k_init(const float* __restrict__ x, const float* __restrict__ W1,
                       const float* __restrict__ b1, float* __restrict__ h) {
    int node = (blockIdx.x * blockDim.x + threadIdx.x) >> 6;
    int lane = threadIdx.x & 63;
    if (node >= NN) return;
    float acc = b1[lane];
    #pragma unroll
    for (int j = 0; j < 8; ++j)
        acc += x[node*8 + j] * W1[lane*8 + j];
    acc = fmaxf(acc, 0.f);
    float ss = acc * acc;
    #pragma unroll
    for (int m = 1; m < 64; m <<= 1) ss += __shfl_xor(ss, m, 64);
    h[node*64 + lane] = acc / sqrtf(ss);
}

// ---------------------------------------------------------------------------
// CSR build: histogram, single-block scan, fill (counting sort by dst).
// ---------------------------------------------------------------------------
__global__ void k_hist(const int* __restrict__ dst, int* __restrict__ deg) {
    int e = blockIdx.x * blockDim.x + threadIdx.x;
    if (e < EE) atomicAdd(&deg[dst[e]], 1);
}

__global__ void k_scan(const int* __restrict__ deg, int* __restrict__ offs,
                       int* __restrict__ cur) {
    __shared__ int part[256];
    int t = threadIdx.x;
    int base = t * 128;
    int s = 0;
    for (int j = 0; j < 128; ++j) s += deg[base + j];
    part[t] = s;
    __syncthreads();
    for (int off = 1; off < 256; off <<= 1) {
        int tmp = (t >= off) ? part[t - off] : 0;
        __syncthreads();
        part[t] += tmp;
        __syncthreads();
    }
    int run = part[t] - s;   // exclusive prefix of this thread's chunk
    for (int j = 0; j < 128; ++j) {
        offs[base + j] = run;
        cur[base + j]  = run;
        run += deg[base + j];
    }
}

__global__ void k_fill(const int* __restrict__ src, const int* __restrict__ dst,
                       int* __restrict__ cur, int* __restrict__ csr) {
    int e = blockIdx.x * blockDim.x + threadIdx.x;
    if (e < EE) {
        int pos = atomicAdd(&cur[dst[e]], 1);
        csr[pos] = src[e];
    }
}

// ---------------------------------------------------------------------------
// k_layer: fused gather (segment_sum via CSR, no atomics) + update GEMM.
// Block = 32 nodes. Phase 1: each of 4 waves gathers 8 nodes' messages into
// LDS X[n][0:64], copies h[node] into X[n][64:128] (row stride 132 to dodge
// bank conflicts on the GEMM's broadcast reads). Phase 2: GEMM
// hn[n][o] = normalize(relu(sum_kk X[n][kk]*Wc[kk][o] + c[o])).
// Thread tile: 2 nodes x 4 outs, float4 LDS reads both operands.
// ---------------------------------------------------------------------------
__global__ void __launch_bounds__(256) k_layer(
        const float* __restrict__ Wc, const float* __restrict__ h,
        const int* __restrict__ offs, const int* __restrict__ deg,
        const int* __restrict__ csr, float* __restrict__ hn) {
    __shared__ float Wl[8192];       // [kk][o], stride 64
    __shared__ float Xl[32 * 132];   // [n][kk], stride 132
    int t = threadIdx.x;
    int nbase = blockIdx.x * 32;

    // stage W (straight copy, float4)
    for (int i = t * 4; i < 8192; i += 1024)
        *(float4*)&Wl[i] = *(const float4*)&Wc[i];

    // gather phase: wave wv handles nodes wv*8 .. wv*8+7
    int lane = t & 63, wv = t >> 6;
    for (int j = 0; j < 8; ++j) {
        int n = wv * 8 + j;
        int gn = nbase + n;
        int st = offs[gn], de = deg[gn];
        float acc = 0.f;
        int e = 0;
        for (; e + 1 < de; e += 2) {
            int s0 = csr[st + e], s1 = csr[st + e + 1];
            float v0 = h[s0*64 + lane];
            float v1 = h[s1*64 + lane];
            acc += v0 + v1;
        }
        if (e < de) acc += h[csr[st + e]*64 + lane];
        Xl[n*132 + lane]      = acc;             // message sum
        Xl[n*132 + 64 + lane] = h[gn*64 + lane]; // own features
    }
    __syncthreads();

    // GEMM phase
    int tc = t & 15, tr = t >> 4;    // tc: o-col group, tr: node-row group
    int o0 = tc * 4, n0 = tr * 2;
    float4 c4 = *(const float4*)&Wc[8192 + o0];
    float acc0[4] = {0.f,0.f,0.f,0.f};
    float acc1[4] = {0.f,0.f,0.f,0.f};
    #pragma unroll 4
    for (int kk = 0; kk < 128; kk += 4) {
        float4 w0 = *(float4*)&Wl[(kk+0)*64 + o0];
        float4 w1 = *(float4*)&Wl[(kk+1)*64 + o0];
        float4 w2 = *(float4*)&Wl[(kk+2)*64 + o0];
        float4 w3 = *(float4*)&Wl[(kk+3)*64 + o0];
        float4 x0 = *(float4*)&Xl[(n0+0)*132 + kk];
        float4 x1 = *(float4*)&Xl[(n0+1)*132 + kk];
        acc0[0] += x0.x*w0.x + x0.y*w1.x + x0.z*w2.x + x0.w*w3.x;
        acc0[1] += x0.x*w0.y + x0.y*w1.y + x0.z*w2.y + x0.w*w3.y;
        acc0[2] += x0.x*w0.z + x0.y*w1.z + x0.z*w2.z + x0.w*w3.z;
        acc0[3] += x0.x*w0.w + x0.y*w1.w + x0.z*w2.w + x0.w*w3.w;
        acc1[0] += x1.x*w0.x + x1.y*w1.x + x1.z*w2.x + x1.w*w3.x;
        acc1[1] += x1.x*w0.y + x1.y*w1.y + x1.z*w2.y + x1.w*w3.y;
        acc1[2] += x1.x*w0.z + x1.y*w1.z + x1.z*w2.z + x1.w*w3.z;
        acc1[3] += x1.x*w0.w + x1.y*w1.w + x1.z*w2.w + x1.w*w3.w;
    }

    // epilogue: relu + bias, row L2-normalize (reduce across 16 tc lanes)
    #pragma unroll
    for (int jn = 0; jn < 2; ++jn) {
        float* a = jn ? acc1 : acc0;
        float v0 = fmaxf(a[0] + c4.x, 0.f);
        float v1 = fmaxf(a[1] + c4.y, 0.f);
        float v2 = fmaxf(a[2] + c4.z, 0.f);
        float v3 = fmaxf(a[3] + c4.w, 0.f);
        float ss = v0*v0 + v1*v1 + v2*v2 + v3*v3;
        ss += __shfl_xor(ss, 1, 64);
        ss += __shfl_xor(ss, 2, 64);
        ss += __shfl_xor(ss, 4, 64);
        ss += __shfl_xor(ss, 8, 64);
        float r = 1.0f / sqrtf(ss);
        float4 outv = make_float4(v0*r, v1*r, v2*r, v3*r);
        *(float4*)&hn[(long)(nbase + n0 + jn)*64 + o0] = outv;
    }
}

// ---------------------------------------------------------------------------
// k_outerT: Tt[g][i*64+o] = sum_j W5[o*4096 + i*64 + j] * last[g][j]
// ---------------------------------------------------------------------------
__global__ void k_outerT(const float* __restrict__ h, const float* __restrict__ W5,
                         float* __restrict__ Tt) {
    int gg = blockIdx.x >> 3;      // graph group (8 graphs)
    int ic = blockIdx.x & 7;       // i-chunk (8 i)
    __shared__ float last8[8][64];
    int tid = threadIdx.x;
    for (int idx = tid; idx < 512; idx += 256) {
        int g8 = idx >> 6, j = idx & 63;
        last8[g8][j] = h[((long)(gg*8 + g8)*128 + 127)*64 + j];
    }
    __syncthreads();
    int o = tid & 63;
    int sub = tid >> 6;
    for (int d = 0; d < 2; ++d) {
        int i = ic*8 + sub*2 + d;
        float acc[8] = {0.f,0.f,0.f,0.f,0.f,0.f,0.f,0.f};
        for (int j = 0; j < 64; ++j) {
            float w = W5[(long)o*4096 + i*64 + j];
            #pragma unroll
            for (int g8 = 0; g8 < 8; ++g8) acc[g8] += w * last8[g8][j];
        }
        #pragma unroll
        for (int g8 = 0; g8 < 8; ++g8)
            Tt[(long)(gg*8 + g8)*4096 + i*64 + o] = acc[g8];
    }
}

// ---------------------------------------------------------------------------
// k_readout: per-graph GEMM chain, 2 blocks/graph, 2 p-tiles of 32 each.
// GEMM1: y[p][o] = b5[o] + sum_i O[p][i]*T[i][o]     (thread: 2p x 4o)
// GEMM2: hid[p][q] = relu(bd1[q] + sum_o y[p][o]*Wd1[q][o]) (thread: 4p x 4q)
// out[p] = bd2 + sum_q Wd2[q]*hid[p][q]  (shfl reduce over 32 q-lanes)
// O and Y share one LDS buffer (stride 68), barriers between phases.
// ---------------------------------------------------------------------------
__global__ void __launch_bounds__(256) k_readout(
        const float* __restrict__ h, const float* __restrict__ Tt,
        const float* __restrict__ b5, const float* __restrict__ Wd1,
        const float* __restrict__ bd1, const float* __restrict__ Wd2,
        const float* __restrict__ bd2, float* __restrict__ out) {
    __shared__ float Tl[4096];       // [i][o], stride 64
    __shared__ float W1t[8192];      // [o][q], stride 128
    __shared__ float OY[32 * 68];    // [p][i] then [p][o], stride 68
    int t = threadIdx.x;
    int g = blockIdx.x >> 1, half = blockIdx.x & 1;

    for (int i = t * 4; i < 4096; i += 1024)
        *(float4*)&Tl[i] = *(const float4*)&Tt[(long)g*4096 + i];
    for (int idx = t; idx < 8192; idx += 256) {
        int o = idx >> 7, q = idx & 127;
        W1t[o*128 + q] = Wd1[q*64 + o];
    }

    int tc = t & 15, tr = t >> 4;      // GEMM1 map
    int o0 = tc * 4, p0 = tr * 2;
    int tc2 = t & 31, tr2 = t >> 5;    // GEMM2 map
    int q0 = tc2 * 4, pp0 = tr2 * 4;
    float4 b5_4  = *(const float4*)&b5[o0];
    float4 bd1_4 = *(const float4*)&bd1[q0];
    float4 wd2_4 = *(const float4*)&Wd2[q0];
    float bd2v = bd2[0];

    for (int pt = half*2; pt < half*2 + 2; ++pt) {
        int pbase = pt * 32;
        __syncthreads();  // previous tile's GEMM2 reads done; T/W1t staged
        for (int idx = t; idx < 512; idx += 256) {
            int p = idx >> 4, c = (idx & 15) * 4;
            *(float4*)&OY[p*68 + c] =
                *(const float4*)&h[((long)g*128 + pbase + p)*64 + c];
        }
        __syncthreads();

        // GEMM1
        float a10[4] = {0.f,0.f,0.f,0.f};
        float a11[4] = {0.f,0.f,0.f,0.f};
        #pragma unroll 4
        for (int i = 0; i < 64; i += 4) {
            float4 w0 = *(float4*)&Tl[(i+0)*64 + o0];
            float4 w1 = *(float4*)&Tl[(i+1)*64 + o0];
            float4 w2 = *(float4*)&Tl[(i+2)*64 + o0];
            float4 w3 = *(float4*)&Tl[(i+3)*64 + o0];
            float4 x0 = *(float4*)&OY[(p0+0)*68 + i];
            float4 x1 = *(float4*)&OY[(p0+1)*68 + i];
            a10[0] += x0.x*w0.x + x0.y*w1.x + x0.z*w2.x + x0.w*w3.x;
            a10[1] += x0.x*w0.y + x0.y*w1.y + x0.z*w2.y + x0.w*w3.y;
            a10[2] += x0.x*w0.z + x0.y*w1.z + x0.z*w2.z + x0.w*w3.z;
            a10[3] += x0.x*w0.w + x0.y*w1.w + x0.z*w2.w + x0.w*w3.w;
            a11[0] += x1.x*w0.x + x1.y*w1.x + x1.z*w2.x + x1.w*w3.x;
            a11[1] += x1.x*w0.y + x1.y*w1.y + x1.z*w2.y + x1.w*w3.y;
            a11[2] += x1.x*w0.z + x1.y*w1.z + x1.z*w2.z + x1.w*w3.z;
            a11[3] += x1.x*w0.w + x1.y*w1.w + x1.z*w2.w + x1.w*w3.w;
        }
        __syncthreads();  // all reads of O done; OY becomes Y

        float4 y0 = make_float4(a10[0]+b5_4.x, a10[1]+b5_4.y, a10[2]+b5_4.z, a10[3]+b5_4.w);
        float4 y1 = make_float4(a11[0]+b5_4.x, a11[1]+b5_4.y, a11[2]+b5_4.z, a11[3]+b5_4.w);
        *(float4*)&OY[(p0+0)*68 + o0] = y0;
        *(float4*)&OY[(p0+1)*68 + o0] = y1;
        __syncthreads();

        // GEMM2
        float a2[4][4] = {};
        #pragma unroll 4
        for (int o = 0; o < 64; o += 4) {
            float4 w0 = *(float4*)&W1t[(o+0)*128 + q0];
            float4 w1 = *(float4*)&W1t[(o+1)*128 + q0];
            float4 w2 = *(float4*)&W1t[(o+2)*128 + q0];
            float4 w3 = *(float4*)&W1t[(o+3)*128 + q0];
            #pragma unroll
            for (int jp = 0; jp < 4; ++jp) {
                float4 yv = *(float4*)&OY[(pp0+jp)*68 + o];
                a2[jp][0] += yv.x*w0.x + yv.y*w1.x + yv.z*w2.x + yv.w*w3.x;
                a2[jp][1] += yv.x*w0.y + yv.y*w1.y + yv.z*w2.y + yv.w*w3.y;
                a2[jp][2] += yv.x*w0.z + yv.y*w1.z + yv.z*w2.z + yv.w*w3.z;
                a2[jp][3] += yv.x*w0.w + yv.y*w1.w + yv.z*w2.w + yv.w*w3.w;
            }
        }

        // epilogue: relu, dot with Wd2, reduce over 32 q-lanes
        #pragma unroll
        for (int jp = 0; jp < 4; ++jp) {
            float s = wd2_4.x * fmaxf(a2[jp][0] + bd1_4.x, 0.f)
                    + wd2_4.y * fmaxf(a2[jp][1] + bd1_4.y, 0.f)
                    + wd2_4.z * fmaxf(a2[jp][2] + bd1_4.z, 0.f)
                    + wd2_4.w * fmaxf(a2[jp][3] + bd1_4.w, 0.f);
            s += __shfl_xor(s, 1, 64);
            s += __shfl_xor(s, 2, 64);
            s += __shfl_xor(s, 4, 64);
            s += __shfl_xor(s, 8, 64);
            s += __shfl_xor(s, 16, 64);
            if (tc2 == 0) {
                int p = pbase + pp0 + jp;
                if (p < 127) out[g*127 + p] = s + bd2v;
            }
        }
    }
}

extern "C" void kernel_launch(void* const* d_in, const int* in_sizes, int n_in,
                              void* d_out, int out_size, void* d_ws, size_t ws_size,
                              hipStream_t stream) {
    const float* x   = (const float*)d_in[0];
    const int*   ei  = (const int*)d_in[1];   // [2][E] int32
    const float* W1  = (const float*)d_in[4];
    const float* b1  = (const float*)d_in[5];
    const float* W2  = (const float*)d_in[6];
    const float* b2  = (const float*)d_in[7];
    const float* W3  = (const float*)d_in[8];
    const float* b3  = (const float*)d_in[9];
    const float* W4  = (const float*)d_in[10];
    const float* b4  = (const float*)d_in[11];
    const float* W5  = (const float*)d_in[12];
    const float* b5  = (const float*)d_in[13];
    const float* Wd1 = (const float*)d_in[14];
    const float* bd1 = (const float*)d_in[15];
    const float* Wd2 = (const float*)d_in[16];
    const float* bd2 = (const float*)d_in[17];
    float* out = (float*)d_out;

    float* ws  = (float*)d_ws;
    float* h0  = ws;                        // 2^21 floats
    float* h1  = ws + 2097152;              // 2^21 floats
    float* Tt  = ws + 4194304;              // 2^20 floats
    float* Wc  = ws + 5242880;              // 8448 floats (8192 + c + pad)
    int*   deg  = (int*)(ws + 5251328);
    int*   offs = deg + NN;
    int*   cur  = offs + NN;
    int*   csr  = cur + NN;                 // EE ints

    const int* src = ei;
    const int* dst = ei + EE;

    k_prep<<<32, 256, 0, stream>>>(W2, b2, W3, b3, W4, b4, Wc);
    k_init<<<NN/4, 256, 0, stream>>>(x, W1, b1, h0);

    hipMemsetAsync(deg, 0, NN * sizeof(int), stream);
    k_hist<<<EE/256, 256, 0, stream>>>(dst, deg);
    k_scan<<<1, 256, 0, stream>>>(deg, offs, cur);
    k_fill<<<EE/256, 256, 0, stream>>>(src, dst, cur, csr);

    float* hc = h0; float* hn = h1;
    for (int l = 0; l < 3; ++l) {
        k_layer<<<NN/32, 256, 0, stream>>>(Wc, hc, offs, deg, csr, hn);
        float* tmp = hc; hc = hn; hn = tmp;
    }

    k_outerT<<<256, 256, 0, stream>>>(hc, W5, Tt);
    k_readout<<<512, 256, 0, stream>>>(hc, Tt, b5, Wd1, bd1, Wd2, bd2, out);
}

// Round 3
// 379.428 us; speedup vs baseline: 2.0793x; 1.3014x over previous
//
#include <hip/hip_runtime.h>
#include <hip/hip_bf16.h>

#define NN 32768
#define EE 524288
#define GG 256
#define PP 128

__device__ __forceinline__ float4 shfl_xor_f4(float4 v, int m) {
    return make_float4(__shfl_xor(v.x, m, 64), __shfl_xor(v.y, m, 64),
                       __shfl_xor(v.z, m, 64), __shfl_xor(v.w, m, 64));
}

// ---------------------------------------------------------------------------
// k_prep: fold W2/W3/W4/b2/b3/b4 into Wc[kk][o] (kk-major, 128x64) + c[o].
// ---------------------------------------------------------------------------
__global__ void k_prep(const float* __restrict__ W2, const float* __restrict__ b2,
                       const float* __restrict__ W3, const float* __restrict__ b3,
                       const float* __restrict__ W4, const float* __restrict__ b4,
                       float* __restrict__ Wc) {
    int idx = blockIdx.x * blockDim.x + threadIdx.x;  // 32*256 = 8192
    int kk = idx >> 6, o = idx & 63;
    float a = 0.f;
    if (kk < 64) {
        for (int j = 0; j < 64; ++j) a += W4[o*128 + j] * W3[j*64 + kk];
    } else {
        int k2 = kk - 64;
        for (int j = 0; j < 64; ++j) a += W4[o*128 + 64 + j] * W2[j*64 + k2];
    }
    Wc[kk*64 + o] = a;
    if (idx < 64) {
        float c = b4[idx];
        for (int j = 0; j < 64; ++j)
            c += W4[idx*128 + j]*b3[j] + W4[idx*128 + 64 + j]*b2[j];
        Wc[8192 + idx] = c;
    }
}

// ---------------------------------------------------------------------------
// k_twd1: one-shot transpose Wd1[128][64] -> Wd1t[64][128] (coalesced both
// sides via padded LDS tile). Kills the per-block strided global reads that
// k_readout previously did 512 times.
// ---------------------------------------------------------------------------
__global__ void k_twd1(const float* __restrict__ Wd1, float* __restrict__ Wd1t) {
    __shared__ float tile[128 * 65];
    int t = threadIdx.x;
    for (int idx = t; idx < 8192; idx += 256) {
        int q = idx >> 6, o = idx & 63;
        tile[q*65 + o] = Wd1[idx];
    }
    __syncthreads();
    for (int idx = t; idx < 8192; idx += 256) {
        int o = idx >> 7, q = idx & 127;
        Wd1t[idx] = tile[q*65 + o];
    }
}

// ---------------------------------------------------------------------------
// k_init: h = normalize(relu(x @ W1.T + b1)). One wave per node, lane = out.
// ---------------------------------------------------------------------------
__global__ void k_init(const float* __restrict__ x, const float* __restrict__ W1,
                       const float* __restrict__ b1, float* __restrict__ h) {
    int node = (blockIdx.x * blockDim.x + threadIdx.x) >> 6;
    int lane = threadIdx.x & 63;
    if (node >= NN) return;
    float acc = b1[lane];
    #pragma unroll
    for (int j = 0; j < 8; ++j)
        acc += x[node*8 + j] * W1[lane*8 + j];
    acc = fmaxf(acc, 0.f);
    float ss = acc * acc;
    #pragma unroll
    for (int m = 1; m < 64; m <<= 1) ss += __shfl_xor(ss, m, 64);
    h[node*64 + lane] = acc / sqrtf(ss);
}

// ---------------------------------------------------------------------------
// CSR build: histogram, single-block scan, fill (counting sort by dst).
// ---------------------------------------------------------------------------
__global__ void k_hist(const int* __restrict__ dst, int* __restrict__ deg) {
    int e = blockIdx.x * blockDim.x + threadIdx.x;
    if (e < EE) atomicAdd(&deg[dst[e]], 1);
}

__global__ void k_scan(const int* __restrict__ deg, int* __restrict__ offs,
                       int* __restrict__ cur) {
    __shared__ int part[256];
    int t = threadIdx.x;
    int base = t * 128;
    int s = 0;
    for (int j = 0; j < 128; ++j) s += deg[base + j];
    part[t] = s;
    __syncthreads();
    for (int off = 1; off < 256; off <<= 1) {
        int tmp = (t >= off) ? part[t - off] : 0;
        __syncthreads();
        part[t] += tmp;
        __syncthreads();
    }
    int run = part[t] - s;   // exclusive prefix of this thread's chunk
    for (int j = 0; j < 128; ++j) {
        offs[base + j] = run;
        cur[base + j]  = run;
        run += deg[base + j];
    }
}

__global__ void k_fill(const int* __restrict__ src, const int* __restrict__ dst,
                       int* __restrict__ cur, int* __restrict__ csr) {
    int e = blockIdx.x * blockDim.x + threadIdx.x;
    if (e < EE) {
        int pos = atomicAdd(&cur[dst[e]], 1);
        csr[pos] = src[e];
    }
}

// ---------------------------------------------------------------------------
// k_layer: fused gather (segment_sum via CSR) + update GEMM.
// Gather: lane split fg=lane&15 (4 features as float4), es=lane>>4 (4 edge
// slots). One global_load_dwordx4 covers 4 edges (1 KiB/wave-instr); main
// loop keeps 4 loads (16 edges) in flight. Cross-es reduce via shfl_xor
// 16/32. ~16x more gather bytes in flight per wave than the 2-edge scheme.
// GEMM: hn[n][o] = normalize(relu(sum_kk X[n][kk]*Wc[kk][o] + c[o])),
// thread tile 2 nodes x 4 outs, float4 LDS reads both operands.
// ---------------------------------------------------------------------------
__global__ void __launch_bounds__(256) k_layer(
        const float* __restrict__ Wc, const float* __restrict__ h,
        const int* __restrict__ offs, const int* __restrict__ deg,
        const int* __restrict__ csr, float* __restrict__ hn) {
    __shared__ float Wl[8192];       // [kk][o], stride 64
    __shared__ float Xl[32 * 132];   // [n][kk], stride 132
    int t = threadIdx.x;
    int nbase = blockIdx.x * 32;

    // stage W (straight copy, float4)
    for (int i = t * 4; i < 8192; i += 1024)
        *(float4*)&Wl[i] = *(const float4*)&Wc[i];

    // gather phase: wave wv handles nodes wv*8 .. wv*8+7
    int lane = t & 63, wv = t >> 6;
    int fg4 = (lane & 15) * 4, es = lane >> 4;
    for (int j = 0; j < 8; ++j) {
        int n = wv * 8 + j;
        int gn = nbase + n;
        int st = offs[gn], de = deg[gn];
        float4 acc = make_float4(0.f, 0.f, 0.f, 0.f);
        int e = 0;
        for (; e + 16 <= de; e += 16) {
            int i0 = csr[st + e + es];
            int i1 = csr[st + e + 4 + es];
            int i2 = csr[st + e + 8 + es];
            int i3 = csr[st + e + 12 + es];
            float4 v0 = *(const float4*)&h[(long)i0*64 + fg4];
            float4 v1 = *(const float4*)&h[(long)i1*64 + fg4];
            float4 v2 = *(const float4*)&h[(long)i2*64 + fg4];
            float4 v3 = *(const float4*)&h[(long)i3*64 + fg4];
            acc.x += (v0.x + v1.x) + (v2.x + v3.x);
            acc.y += (v0.y + v1.y) + (v2.y + v3.y);
            acc.z += (v0.z + v1.z) + (v2.z + v3.z);
            acc.w += (v0.w + v1.w) + (v2.w + v3.w);
        }
        for (; e < de; e += 4) {           // tail, 4 edges/step, lane-masked
            if (e + es < de) {
                int s0 = csr[st + e + es];
                float4 v = *(const float4*)&h[(long)s0*64 + fg4];
                acc.x += v.x; acc.y += v.y; acc.z += v.z; acc.w += v.w;
            }
        }
        float4 r1 = shfl_xor_f4(acc, 16);
        acc.x += r1.x; acc.y += r1.y; acc.z += r1.z; acc.w += r1.w;
        float4 r2 = shfl_xor_f4(acc, 32);
        acc.x += r2.x; acc.y += r2.y; acc.z += r2.z; acc.w += r2.w;
        if (es == 0) *(float4*)&Xl[n*132 + fg4] = acc;      // message sum
        Xl[n*132 + 64 + lane] = h[(long)gn*64 + lane];      // own features
    }
    __syncthreads();

    // GEMM phase
    int tc = t & 15, tr = t >> 4;
    int o0 = tc * 4, n0 = tr * 2;
    float4 c4 = *(const float4*)&Wc[8192 + o0];
    float acc0[4] = {0.f,0.f,0.f,0.f};
    float acc1[4] = {0.f,0.f,0.f,0.f};
    #pragma unroll 4
    for (int kk = 0; kk < 128; kk += 4) {
        float4 w0 = *(float4*)&Wl[(kk+0)*64 + o0];
        float4 w1 = *(float4*)&Wl[(kk+1)*64 + o0];
        float4 w2 = *(float4*)&Wl[(kk+2)*64 + o0];
        float4 w3 = *(float4*)&Wl[(kk+3)*64 + o0];
        float4 x0 = *(float4*)&Xl[(n0+0)*132 + kk];
        float4 x1 = *(float4*)&Xl[(n0+1)*132 + kk];
        acc0[0] += x0.x*w0.x + x0.y*w1.x + x0.z*w2.x + x0.w*w3.x;
        acc0[1] += x0.x*w0.y + x0.y*w1.y + x0.z*w2.y + x0.w*w3.y;
        acc0[2] += x0.x*w0.z + x0.y*w1.z + x0.z*w2.z + x0.w*w3.z;
        acc0[3] += x0.x*w0.w + x0.y*w1.w + x0.z*w2.w + x0.w*w3.w;
        acc1[0] += x1.x*w0.x + x1.y*w1.x + x1.z*w2.x + x1.w*w3.x;
        acc1[1] += x1.x*w0.y + x1.y*w1.y + x1.z*w2.y + x1.w*w3.y;
        acc1[2] += x1.x*w0.z + x1.y*w1.z + x1.z*w2.z + x1.w*w3.z;
        acc1[3] += x1.x*w0.w + x1.y*w1.w + x1.z*w2.w + x1.w*w3.w;
    }

    // epilogue: relu + bias, row L2-normalize (reduce across 16 tc lanes)
    #pragma unroll
    for (int jn = 0; jn < 2; ++jn) {
        float* a = jn ? acc1 : acc0;
        float v0 = fmaxf(a[0] + c4.x, 0.f);
        float v1 = fmaxf(a[1] + c4.y, 0.f);
        float v2 = fmaxf(a[2] + c4.z, 0.f);
        float v3 = fmaxf(a[3] + c4.w, 0.f);
        float ss = v0*v0 + v1*v1 + v2*v2 + v3*v3;
        ss += __shfl_xor(ss, 1, 64);
        ss += __shfl_xor(ss, 2, 64);
        ss += __shfl_xor(ss, 4, 64);
        ss += __shfl_xor(ss, 8, 64);
        float r = 1.0f / sqrtf(ss);
        float4 outv = make_float4(v0*r, v1*r, v2*r, v3*r);
        *(float4*)&hn[(long)(nbase + n0 + jn)*64 + o0] = outv;
    }
}

// ---------------------------------------------------------------------------
// k_outerT: Tt[g][i*64+o] = sum_j W5[o*4096 + i*64 + j] * last[g][j]
// ---------------------------------------------------------------------------
__global__ void k_outerT(const float* __restrict__ h, const float* __restrict__ W5,
                         float* __restrict__ Tt) {
    int gg = blockIdx.x >> 3;      // graph group (8 graphs)
    int ic = blockIdx.x & 7;       // i-chunk (8 i)
    __shared__ float last8[8][64];
    int tid = threadIdx.x;
    for (int idx = tid; idx < 512; idx += 256) {
        int g8 = idx >> 6, j = idx & 63;
        last8[g8][j] = h[((long)(gg*8 + g8)*128 + 127)*64 + j];
    }
    __syncthreads();
    int o = tid & 63;
    int sub = tid >> 6;
    for (int d = 0; d < 2; ++d) {
        int i = ic*8 + sub*2 + d;
        float acc[8] = {0.f,0.f,0.f,0.f,0.f,0.f,0.f,0.f};
        for (int j = 0; j < 64; ++j) {
            float w = W5[(long)o*4096 + i*64 + j];
            #pragma unroll
            for (int g8 = 0; g8 < 8; ++g8) acc[g8] += w * last8[g8][j];
        }
        #pragma unroll
        for (int g8 = 0; g8 < 8; ++g8)
            Tt[(long)(gg*8 + g8)*4096 + i*64 + o] = acc[g8];
    }
}

// ---------------------------------------------------------------------------
// k_readout: per-graph GEMM chain, 2 blocks/graph, 2 p-tiles of 32 each.
// GEMM1: y[p][o] = b5[o] + sum_i O[p][i]*T[i][o]     (thread: 2p x 4o)
// GEMM2: hid[p][q] = relu(bd1[q] + sum_o y[p][o]*Wd1t[o][q]) (thread: 4p x 4q)
// out[p] = bd2 + sum_q Wd2[q]*hid[p][q]  (shfl reduce over 32 q-lanes)
// ---------------------------------------------------------------------------
__global__ void __launch_bounds__(256) k_readout(
        const float* __restrict__ h, const float* __restrict__ Tt,
        const float* __restrict__ b5, const float* __restrict__ Wd1t,
        const float* __restrict__ bd1, const float* __restrict__ Wd2,
        const float* __restrict__ bd2, float* __restrict__ out) {
    __shared__ float Tl[4096];       // [i][o], stride 64
    __shared__ float W1t[8192];      // [o][q], stride 128
    __shared__ float OY[32 * 68];    // [p][i] then [p][o], stride 68
    int t = threadIdx.x;
    int g = blockIdx.x >> 1, half = blockIdx.x & 1;

    for (int i = t * 4; i < 4096; i += 1024)
        *(float4*)&Tl[i] = *(const float4*)&Tt[(long)g*4096 + i];
    for (int i = t * 4; i < 8192; i += 1024)
        *(float4*)&W1t[i] = *(const float4*)&Wd1t[i];

    int tc = t & 15, tr = t >> 4;      // GEMM1 map
    int o0 = tc * 4, p0 = tr * 2;
    int tc2 = t & 31, tr2 = t >> 5;    // GEMM2 map
    int q0 = tc2 * 4, pp0 = tr2 * 4;
    float4 b5_4  = *(const float4*)&b5[o0];
    float4 bd1_4 = *(const float4*)&bd1[q0];
    float4 wd2_4 = *(const float4*)&Wd2[q0];
    float bd2v = bd2[0];

    for (int pt = half*2; pt < half*2 + 2; ++pt) {
        int pbase = pt * 32;
        __syncthreads();  // previous tile's GEMM2 reads done; T/W1t staged
        for (int idx = t; idx < 512; idx += 256) {
            int p = idx >> 4, c = (idx & 15) * 4;
            *(float4*)&OY[p*68 + c] =
                *(const float4*)&h[((long)g*128 + pbase + p)*64 + c];
        }
        __syncthreads();

        // GEMM1
        float a10[4] = {0.f,0.f,0.f,0.f};
        float a11[4] = {0.f,0.f,0.f,0.f};
        #pragma unroll 4
        for (int i = 0; i < 64; i += 4) {
            float4 w0 = *(float4*)&Tl[(i+0)*64 + o0];
            float4 w1 = *(float4*)&Tl[(i+1)*64 + o0];
            float4 w2 = *(float4*)&Tl[(i+2)*64 + o0];
            float4 w3 = *(float4*)&Tl[(i+3)*64 + o0];
            float4 x0 = *(float4*)&OY[(p0+0)*68 + i];
            float4 x1 = *(float4*)&OY[(p0+1)*68 + i];
            a10[0] += x0.x*w0.x + x0.y*w1.x + x0.z*w2.x + x0.w*w3.x;
            a10[1] += x0.x*w0.y + x0.y*w1.y + x0.z*w2.y + x0.w*w3.y;
            a10[2] += x0.x*w0.z + x0.y*w1.z + x0.z*w2.z + x0.w*w3.z;
            a10[3] += x0.x*w0.w + x0.y*w1.w + x0.z*w2.w + x0.w*w3.w;
            a11[0] += x1.x*w0.x + x1.y*w1.x + x1.z*w2.x + x1.w*w3.x;
            a11[1] += x1.x*w0.y + x1.y*w1.y + x1.z*w2.y + x1.w*w3.y;
            a11[2] += x1.x*w0.z + x1.y*w1.z + x1.z*w2.z + x1.w*w3.z;
            a11[3] += x1.x*w0.w + x1.y*w1.w + x1.z*w2.w + x1.w*w3.w;
        }
        __syncthreads();  // all reads of O done; OY becomes Y

        float4 y0 = make_float4(a10[0]+b5_4.x, a10[1]+b5_4.y, a10[2]+b5_4.z, a10[3]+b5_4.w);
        float4 y1 = make_float4(a11[0]+b5_4.x, a11[1]+b5_4.y, a11[2]+b5_4.z, a11[3]+b5_4.w);
        *(float4*)&OY[(p0+0)*68 + o0] = y0;
        *(float4*)&OY[(p0+1)*68 + o0] = y1;
        __syncthreads();

        // GEMM2
        float a2[4][4] = {};
        #pragma unroll 4
        for (int o = 0; o < 64; o += 4) {
            float4 w0 = *(float4*)&W1t[(o+0)*128 + q0];
            float4 w1 = *(float4*)&W1t[(o+1)*128 + q0];
            float4 w2 = *(float4*)&W1t[(o+2)*128 + q0];
            float4 w3 = *(float4*)&W1t[(o+3)*128 + q0];
            #pragma unroll
            for (int jp = 0; jp < 4; ++jp) {
                float4 yv = *(float4*)&OY[(pp0+jp)*68 + o];
                a2[jp][0] += yv.x*w0.x + yv.y*w1.x + yv.z*w2.x + yv.w*w3.x;
                a2[jp][1] += yv.x*w0.y + yv.y*w1.y + yv.z*w2.y + yv.w*w3.y;
                a2[jp][2] += yv.x*w0.z + yv.y*w1.z + yv.z*w2.z + yv.w*w3.z;
                a2[jp][3] += yv.x*w0.w + yv.y*w1.w + yv.z*w2.w + yv.w*w3.w;
            }
        }

        // epilogue: relu, dot with Wd2, reduce over 32 q-lanes
        #pragma unroll
        for (int jp = 0; jp < 4; ++jp) {
            float s = wd2_4.x * fmaxf(a2[jp][0] + bd1_4.x, 0.f)
                    + wd2_4.y * fmaxf(a2[jp][1] + bd1_4.y, 0.f)
                    + wd2_4.z * fmaxf(a2[jp][2] + bd1_4.z, 0.f)
                    + wd2_4.w * fmaxf(a2[jp][3] + bd1_4.w, 0.f);
            s += __shfl_xor(s, 1, 64);
            s += __shfl_xor(s, 2, 64);
            s += __shfl_xor(s, 4, 64);
            s += __shfl_xor(s, 8, 64);
            s += __shfl_xor(s, 16, 64);
            if (tc2 == 0) {
                int p = pbase + pp0 + jp;
                if (p < 127) out[g*127 + p] = s + bd2v;
            }
        }
    }
}

extern "C" void kernel_launch(void* const* d_in, const int* in_sizes, int n_in,
                              void* d_out, int out_size, void* d_ws, size_t ws_size,
                              hipStream_t stream) {
    const float* x   = (const float*)d_in[0];
    const int*   ei  = (const int*)d_in[1];   // [2][E] int32
    const float* W1  = (const float*)d_in[4];
    const float* b1  = (const float*)d_in[5];
    const float* W2  = (const float*)d_in[6];
    const float* b2  = (const float*)d_in[7];
    const float* W3  = (const float*)d_in[8];
    const float* b3  = (const float*)d_in[9];
    const float* W4  = (const float*)d_in[10];
    const float* b4  = (const float*)d_in[11];
    const float* W5  = (const float*)d_in[12];
    const float* b5  = (const float*)d_in[13];
    const float* Wd1 = (const float*)d_in[14];
    const float* bd1 = (const float*)d_in[15];
    const float* Wd2 = (const float*)d_in[16];
    const float* bd2 = (const float*)d_in[17];
    float* out = (float*)d_out;

    float* ws  = (float*)d_ws;
    float* h0  = ws;                        // 2^21 floats
    float* h1  = ws + 2097152;              // 2^21 floats
    float* Tt  = ws + 4194304;              // 2^20 floats
    float* Wc  = ws + 5242880;              // 8448 floats (8192 + c + pad)
    float* Wd1t = ws + 5251328;             // 8192 floats
    int*   deg  = (int*)(ws + 5259520);
    int*   offs = deg + NN;
    int*   cur  = offs + NN;
    int*   csr  = cur + NN;                 // EE ints

    const int* src = ei;
    const int* dst = ei + EE;

    k_prep<<<32, 256, 0, stream>>>(W2, b2, W3, b3, W4, b4, Wc);
    k_twd1<<<1, 256, 0, stream>>>(Wd1, Wd1t);
    k_init<<<NN/4, 256, 0, stream>>>(x, W1, b1, h0);

    hipMemsetAsync(deg, 0, NN * sizeof(int), stream);
    k_hist<<<EE/256, 256, 0, stream>>>(dst, deg);
    k_scan<<<1, 256, 0, stream>>>(deg, offs, cur);
    k_fill<<<EE/256, 256, 0, stream>>>(src, dst, cur, csr);

    float* hc = h0; float* hn = h1;
    for (int l = 0; l < 3; ++l) {
        k_layer<<<NN/32, 256, 0, stream>>>(Wc, hc, offs, deg, csr, hn);
        float* tmp = hc; hc = hn; hn = tmp;
    }

    k_outerT<<<256, 256, 0, stream>>>(hc, W5, Tt);
    k_readout<<<512, 256, 0, stream>>>(hc, Tt, b5, Wd1t, bd1, Wd2, bd2, out);
}

// Round 4
// 316.117 us; speedup vs baseline: 2.4957x; 1.2003x over previous
//
#include <hip/hip_runtime.h>
#include <hip/hip_bf16.h>

#define NN 32768
#define EE 524288
#define GG 256
#define PP 128

// ---------------------------------------------------------------------------
// k_prep: fold W2/W3/W4/b2/b3/b4 into Wc[kk][o] (kk-major, 128x64) + c[o].
// ---------------------------------------------------------------------------
__global__ void k_prep(const float* __restrict__ W2, const float* __restrict__ b2,
                       const float* __restrict__ W3, const float* __restrict__ b3,
                       const float* __restrict__ W4, const float* __restrict__ b4,
                       float* __restrict__ Wc) {
    int idx = blockIdx.x * blockDim.x + threadIdx.x;  // 32*256 = 8192
    int kk = idx >> 6, o = idx & 63;
    float a = 0.f;
    if (kk < 64) {
        for (int j = 0; j < 64; ++j) a += W4[o*128 + j] * W3[j*64 + kk];
    } else {
        int k2 = kk - 64;
        for (int j = 0; j < 64; ++j) a += W4[o*128 + 64 + j] * W2[j*64 + k2];
    }
    Wc[kk*64 + o] = a;
    if (idx < 64) {
        float c = b4[idx];
        for (int j = 0; j < 64; ++j)
            c += W4[idx*128 + j]*b3[j] + W4[idx*128 + 64 + j]*b2[j];
        Wc[8192 + idx] = c;
    }
}

// ---------------------------------------------------------------------------
// k_twd1: one-shot transpose Wd1[128][64] -> Wd1t[64][128].
// ---------------------------------------------------------------------------
__global__ void k_twd1(const float* __restrict__ Wd1, float* __restrict__ Wd1t) {
    __shared__ float tile[128 * 65];
    int t = threadIdx.x;
    for (int idx = t; idx < 8192; idx += 256) {
        int q = idx >> 6, o = idx & 63;
        tile[q*65 + o] = Wd1[idx];
    }
    __syncthreads();
    for (int idx = t; idx < 8192; idx += 256) {
        int o = idx >> 7, q = idx & 127;
        Wd1t[idx] = tile[q*65 + o];
    }
}

// ---------------------------------------------------------------------------
// k_init: h = normalize(relu(x @ W1.T + b1)). One wave per node, lane = out.
// ---------------------------------------------------------------------------
__global__ void k_init(const float* __restrict__ x, const float* __restrict__ W1,
                       const float* __restrict__ b1, float* __restrict__ h) {
    int node = (blockIdx.x * blockDim.x + threadIdx.x) >> 6;
    int lane = threadIdx.x & 63;
    if (node >= NN) return;
    float acc = b1[lane];
    #pragma unroll
    for (int j = 0; j < 8; ++j)
        acc += x[node*8 + j] * W1[lane*8 + j];
    acc = fmaxf(acc, 0.f);
    float ss = acc * acc;
    #pragma unroll
    for (int m = 1; m < 64; m <<= 1) ss += __shfl_xor(ss, m, 64);
    h[node*64 + lane] = acc / sqrtf(ss);
}

// ---------------------------------------------------------------------------
// CSR build: histogram, single-block LDS scan (coalesced), fill.
// ---------------------------------------------------------------------------
__global__ void k_hist(const int* __restrict__ dst, int* __restrict__ deg) {
    int e = blockIdx.x * blockDim.x + threadIdx.x;
    if (e < EE) atomicAdd(&deg[dst[e]], 1);
}

// chunk c (128 ints) lives at LDS stride 132 -> per-j bank spread, coalesced IO
__global__ void k_scan(const int* __restrict__ deg, int* __restrict__ offs,
                       int* __restrict__ cur) {
    __shared__ int ld[256 * 132];
    __shared__ int part[256];
    int t = threadIdx.x;
    for (int idx4 = t; idx4 < 8192; idx4 += 256) {
        int c = idx4 >> 5, j = (idx4 & 31) * 4;
        int4 v = ((const int4*)deg)[idx4];
        *(int4*)&ld[c*132 + j] = v;
    }
    __syncthreads();
    int s = 0;
    for (int j = 0; j < 128; ++j) s += ld[t*132 + j];
    part[t] = s;
    __syncthreads();
    for (int off = 1; off < 256; off <<= 1) {
        int tmp = (t >= off) ? part[t - off] : 0;
        __syncthreads();
        part[t] += tmp;
        __syncthreads();
    }
    int run = part[t] - s;   // exclusive prefix of this chunk
    for (int j = 0; j < 128; ++j) {
        int tmp = ld[t*132 + j];
        ld[t*132 + j] = run;
        run += tmp;
    }
    __syncthreads();
    for (int idx4 = t; idx4 < 8192; idx4 += 256) {
        int c = idx4 >> 5, j = (idx4 & 31) * 4;
        int4 v = *(int4*)&ld[c*132 + j];
        ((int4*)offs)[idx4] = v;
        ((int4*)cur)[idx4]  = v;
    }
}

__global__ void k_fill(const int* __restrict__ src, const int* __restrict__ dst,
                       int* __restrict__ cur, int* __restrict__ csr) {
    int e = blockIdx.x * blockDim.x + threadIdx.x;
    if (e < EE) {
        int pos = atomicAdd(&cur[dst[e]], 1);
        csr[pos] = src[e];
    }
}

// ---------------------------------------------------------------------------
// k_gather: segment_sum via CSR. ONE NODE PER WAVE (32768 independent waves,
// no LDS, no barriers). Lane split: fg4=(lane&15)*4 features (float4),
// es=lane>>4 edge slot. Branchless 16-edge rounds: 4 independent index loads
// + 4 independent 1KB gathers in flight; tail handled by clamp + 0-weight.
// Cross-slot reduce: shfl_xor 16/32. m[node] written by es==0 lanes (256 B).
// ---------------------------------------------------------------------------
__global__ void __launch_bounds__(256) k_gather(
        const float* __restrict__ h, const int* __restrict__ offs,
        const int* __restrict__ deg, const int* __restrict__ csr,
        float* __restrict__ m) {
    int node = (blockIdx.x * blockDim.x + threadIdx.x) >> 6;
    int lane = threadIdx.x & 63;
    int fg4 = (lane & 15) * 4, es = lane >> 4;
    int st = offs[node], de = deg[node];
    float4 acc = make_float4(0.f, 0.f, 0.f, 0.f);
    for (int e = es; e < de; e += 16) {
        int a0 = st + e;                       // e < de: always valid
        int a1 = min(st + e + 4,  EE - 1);
        int a2 = min(st + e + 8,  EE - 1);
        int a3 = min(st + e + 12, EE - 1);
        int i0 = csr[a0], i1 = csr[a1], i2 = csr[a2], i3 = csr[a3];
        float w1 = (e + 4  < de) ? 1.f : 0.f;
        float w2 = (e + 8  < de) ? 1.f : 0.f;
        float w3 = (e + 12 < de) ? 1.f : 0.f;
        float4 v0 = *(const float4*)&h[(long)i0*64 + fg4];
        float4 v1 = *(const float4*)&h[(long)i1*64 + fg4];
        float4 v2 = *(const float4*)&h[(long)i2*64 + fg4];
        float4 v3 = *(const float4*)&h[(long)i3*64 + fg4];
        acc.x += v0.x + w1*v1.x + w2*v2.x + w3*v3.x;
        acc.y += v0.y + w1*v1.y + w2*v2.y + w3*v3.y;
        acc.z += v0.z + w1*v1.z + w2*v2.z + w3*v3.z;
        acc.w += v0.w + w1*v1.w + w2*v2.w + w3*v3.w;
    }
    acc.x += __shfl_xor(acc.x, 16, 64); acc.y += __shfl_xor(acc.y, 16, 64);
    acc.z += __shfl_xor(acc.z, 16, 64); acc.w += __shfl_xor(acc.w, 16, 64);
    acc.x += __shfl_xor(acc.x, 32, 64); acc.y += __shfl_xor(acc.y, 32, 64);
    acc.z += __shfl_xor(acc.z, 32, 64); acc.w += __shfl_xor(acc.w, 32, 64);
    if (es == 0) *(float4*)&m[(long)node*64 + fg4] = acc;
}

// ---------------------------------------------------------------------------
// k_gemm: hn[n][o] = normalize(relu(sum_kk X[n][kk]*Wc[kk][o] + c[o])),
// X = [m | h]. mio holds m on entry and receives hn (SAFE alias: each block
// stages its own 32-row tile into LDS before overwriting it; no cross-block
// access). Thread tile 2 nodes x 4 outs, float4 LDS reads both operands.
// ---------------------------------------------------------------------------
__global__ void __launch_bounds__(256) k_gemm(
        const float* __restrict__ Wc, float* mio,
        const float* __restrict__ hcur) {
    __shared__ float Wl[8192];       // [kk][o], stride 64
    __shared__ float Xl[32 * 132];   // [n][kk], stride 132
    int t = threadIdx.x;
    int nbase = blockIdx.x * 32;

    for (int i = t * 4; i < 8192; i += 1024)
        *(float4*)&Wl[i] = *(const float4*)&Wc[i];
    for (int idx = t; idx < 512; idx += 256) {
        int n = idx >> 4, c = (idx & 15) * 4;
        *(float4*)&Xl[n*132 + c]      = *(const float4*)&mio[(long)(nbase+n)*64 + c];
        *(float4*)&Xl[n*132 + 64 + c] = *(const float4*)&hcur[(long)(nbase+n)*64 + c];
    }
    __syncthreads();

    int tc = t & 15, tr = t >> 4;
    int o0 = tc * 4, n0 = tr * 2;
    float4 c4 = *(const float4*)&Wc[8192 + o0];
    float acc0[4] = {0.f,0.f,0.f,0.f};
    float acc1[4] = {0.f,0.f,0.f,0.f};
    #pragma unroll 4
    for (int kk = 0; kk < 128; kk += 4) {
        float4 w0 = *(float4*)&Wl[(kk+0)*64 + o0];
        float4 w1 = *(float4*)&Wl[(kk+1)*64 + o0];
        float4 w2 = *(float4*)&Wl[(kk+2)*64 + o0];
        float4 w3 = *(float4*)&Wl[(kk+3)*64 + o0];
        float4 x0 = *(float4*)&Xl[(n0+0)*132 + kk];
        float4 x1 = *(float4*)&Xl[(n0+1)*132 + kk];
        acc0[0] += x0.x*w0.x + x0.y*w1.x + x0.z*w2.x + x0.w*w3.x;
        acc0[1] += x0.x*w0.y + x0.y*w1.y + x0.z*w2.y + x0.w*w3.y;
        acc0[2] += x0.x*w0.z + x0.y*w1.z + x0.z*w2.z + x0.w*w3.z;
        acc0[3] += x0.x*w0.w + x0.y*w1.w + x0.z*w2.w + x0.w*w3.w;
        acc1[0] += x1.x*w0.x + x1.y*w1.x + x1.z*w2.x + x1.w*w3.x;
        acc1[1] += x1.x*w0.y + x1.y*w1.y + x1.z*w2.y + x1.w*w3.y;
        acc1[2] += x1.x*w0.z + x1.y*w1.z + x1.z*w2.z + x1.w*w3.z;
        acc1[3] += x1.x*w0.w + x1.y*w1.w + x1.z*w2.w + x1.w*w3.w;
    }

    #pragma unroll
    for (int jn = 0; jn < 2; ++jn) {
        float* a = jn ? acc1 : acc0;
        float v0 = fmaxf(a[0] + c4.x, 0.f);
        float v1 = fmaxf(a[1] + c4.y, 0.f);
        float v2 = fmaxf(a[2] + c4.z, 0.f);
        float v3 = fmaxf(a[3] + c4.w, 0.f);
        float ss = v0*v0 + v1*v1 + v2*v2 + v3*v3;
        ss += __shfl_xor(ss, 1, 64);
        ss += __shfl_xor(ss, 2, 64);
        ss += __shfl_xor(ss, 4, 64);
        ss += __shfl_xor(ss, 8, 64);
        float r = 1.0f / sqrtf(ss);
        float4 outv = make_float4(v0*r, v1*r, v2*r, v3*r);
        *(float4*)&mio[(long)(nbase + n0 + jn)*64 + o0] = outv;
    }
}

// ---------------------------------------------------------------------------
// k_tmat: Tt[g][i*64+o] = sum_j W5[o][i*64+j] * last[g][j].
// 256 blocks, block = 16 consecutive rows r = i*64+o (i fixed per block).
// Thread = graph (256 threads = 256 graphs). W5 staged coalesced (256 B
// rows), last staged [g][j] stride 65, output transposed through LDS so
// global stores are float4.
// ---------------------------------------------------------------------------
__global__ void __launch_bounds__(256) k_tmat(
        const float* __restrict__ h, const float* __restrict__ W5,
        float* __restrict__ Tt) {
    __shared__ float lastL[256 * 65];   // 66.6 KB
    __shared__ float wL[64 * 16];       // [j][rr], 4 KB
    __shared__ float tr[16 * 257];      // [rr][g], 16.4 KB
    int t = threadIdx.x;
    int rb = blockIdx.x * 16;
    int i = rb >> 6, obase = rb & 63;

    for (int idx4 = t; idx4 < 4096; idx4 += 256) {
        int g = idx4 >> 4, c = (idx4 & 15) * 4;
        *(float4*)&lastL[g*65 + c] =
            *(const float4*)&h[((long)g*128 + 127)*64 + c];
    }
    {   // stage W5 slice, transposed to [j][rr]
        int rr = t & 15, j0 = (t >> 4) * 4;
        float4 w = *(const float4*)&W5[(long)(obase + rr)*4096 + i*64 + j0];
        wL[(j0+0)*16 + rr] = w.x;
        wL[(j0+1)*16 + rr] = w.y;
        wL[(j0+2)*16 + rr] = w.z;
        wL[(j0+3)*16 + rr] = w.w;
    }
    __syncthreads();

    int g = t;
    float acc[16] = {};
    for (int j = 0; j < 64; ++j) {
        float lv = lastL[g*65 + j];
        #pragma unroll
        for (int r4 = 0; r4 < 4; ++r4) {
            float4 wv = *(float4*)&wL[j*16 + r4*4];
            acc[r4*4+0] += wv.x * lv;
            acc[r4*4+1] += wv.y * lv;
            acc[r4*4+2] += wv.z * lv;
            acc[r4*4+3] += wv.w * lv;
        }
    }
    #pragma unroll
    for (int rr = 0; rr < 16; ++rr) tr[rr*257 + g] = acc[rr];
    __syncthreads();
    for (int it = 0; it < 4; ++it) {
        int idx = t + it*256;
        int g2 = idx >> 2, c4 = idx & 3;
        float4 v = make_float4(tr[(c4*4+0)*257 + g2], tr[(c4*4+1)*257 + g2],
                               tr[(c4*4+2)*257 + g2], tr[(c4*4+3)*257 + g2]);
        *(float4*)&Tt[(long)g2*4096 + rb + c4*4] = v;
    }
}

// ---------------------------------------------------------------------------
// k_readout: per-graph GEMM chain, 2 blocks/graph, 2 p-tiles of 32 each.
// ---------------------------------------------------------------------------
__global__ void __launch_bounds__(256) k_readout(
        const float* __restrict__ h, const float* __restrict__ Tt,
        const float* __restrict__ b5, const float* __restrict__ Wd1t,
        const float* __restrict__ bd1, const float* __restrict__ Wd2,
        const float* __restrict__ bd2, float* __restrict__ out) {
    __shared__ float Tl[4096];       // [i][o], stride 64
    __shared__ float W1t[8192];      // [o][q], stride 128
    __shared__ float OY[32 * 68];    // [p][i] then [p][o], stride 68
    int t = threadIdx.x;
    int g = blockIdx.x >> 1, half = blockIdx.x & 1;

    for (int i = t * 4; i < 4096; i += 1024)
        *(float4*)&Tl[i] = *(const float4*)&Tt[(long)g*4096 + i];
    for (int i = t * 4; i < 8192; i += 1024)
        *(float4*)&W1t[i] = *(const float4*)&Wd1t[i];

    int tc = t & 15, tr = t >> 4;      // GEMM1 map
    int o0 = tc * 4, p0 = tr * 2;
    int tc2 = t & 31, tr2 = t >> 5;    // GEMM2 map
    int q0 = tc2 * 4, pp0 = tr2 * 4;
    float4 b5_4  = *(const float4*)&b5[o0];
    float4 bd1_4 = *(const float4*)&bd1[q0];
    float4 wd2_4 = *(const float4*)&Wd2[q0];
    float bd2v = bd2[0];

    for (int pt = half*2; pt < half*2 + 2; ++pt) {
        int pbase = pt * 32;
        __syncthreads();
        for (int idx = t; idx < 512; idx += 256) {
            int p = idx >> 4, c = (idx & 15) * 4;
            *(float4*)&OY[p*68 + c] =
                *(const float4*)&h[((long)g*128 + pbase + p)*64 + c];
        }
        __syncthreads();

        // GEMM1
        float a10[4] = {0.f,0.f,0.f,0.f};
        float a11[4] = {0.f,0.f,0.f,0.f};
        #pragma unroll 4
        for (int i = 0; i < 64; i += 4) {
            float4 w0 = *(float4*)&Tl[(i+0)*64 + o0];
            float4 w1 = *(float4*)&Tl[(i+1)*64 + o0];
            float4 w2 = *(float4*)&Tl[(i+2)*64 + o0];
            float4 w3 = *(float4*)&Tl[(i+3)*64 + o0];
            float4 x0 = *(float4*)&OY[(p0+0)*68 + i];
            float4 x1 = *(float4*)&OY[(p0+1)*68 + i];
            a10[0] += x0.x*w0.x + x0.y*w1.x + x0.z*w2.x + x0.w*w3.x;
            a10[1] += x0.x*w0.y + x0.y*w1.y + x0.z*w2.y + x0.w*w3.y;
            a10[2] += x0.x*w0.z + x0.y*w1.z + x0.z*w2.z + x0.w*w3.z;
            a10[3] += x0.x*w0.w + x0.y*w1.w + x0.z*w2.w + x0.w*w3.w;
            a11[0] += x1.x*w0.x + x1.y*w1.x + x1.z*w2.x + x1.w*w3.x;
            a11[1] += x1.x*w0.y + x1.y*w1.y + x1.z*w2.y + x1.w*w3.y;
            a11[2] += x1.x*w0.z + x1.y*w1.z + x1.z*w2.z + x1.w*w3.z;
            a11[3] += x1.x*w0.w + x1.y*w1.w + x1.z*w2.w + x1.w*w3.w;
        }
        __syncthreads();

        float4 y0 = make_float4(a10[0]+b5_4.x, a10[1]+b5_4.y, a10[2]+b5_4.z, a10[3]+b5_4.w);
        float4 y1 = make_float4(a11[0]+b5_4.x, a11[1]+b5_4.y, a11[2]+b5_4.z, a11[3]+b5_4.w);
        *(float4*)&OY[(p0+0)*68 + o0] = y0;
        *(float4*)&OY[(p0+1)*68 + o0] = y1;
        __syncthreads();

        // GEMM2
        float a2[4][4] = {};
        #pragma unroll 4
        for (int o = 0; o < 64; o += 4) {
            float4 w0 = *(float4*)&W1t[(o+0)*128 + q0];
            float4 w1 = *(float4*)&W1t[(o+1)*128 + q0];
            float4 w2 = *(float4*)&W1t[(o+2)*128 + q0];
            float4 w3 = *(float4*)&W1t[(o+3)*128 + q0];
            #pragma unroll
            for (int jp = 0; jp < 4; ++jp) {
                float4 yv = *(float4*)&OY[(pp0+jp)*68 + o];
                a2[jp][0] += yv.x*w0.x + yv.y*w1.x + yv.z*w2.x + yv.w*w3.x;
                a2[jp][1] += yv.x*w0.y + yv.y*w1.y + yv.z*w2.y + yv.w*w3.y;
                a2[jp][2] += yv.x*w0.z + yv.y*w1.z + yv.z*w2.z + yv.w*w3.z;
                a2[jp][3] += yv.x*w0.w + yv.y*w1.w + yv.z*w2.w + yv.w*w3.w;
            }
        }

        #pragma unroll
        for (int jp = 0; jp < 4; ++jp) {
            float s = wd2_4.x * fmaxf(a2[jp][0] + bd1_4.x, 0.f)
                    + wd2_4.y * fmaxf(a2[jp][1] + bd1_4.y, 0.f)
                    + wd2_4.z * fmaxf(a2[jp][2] + bd1_4.z, 0.f)
                    + wd2_4.w * fmaxf(a2[jp][3] + bd1_4.w, 0.f);
            s += __shfl_xor(s, 1, 64);
            s += __shfl_xor(s, 2, 64);
            s += __shfl_xor(s, 4, 64);
            s += __shfl_xor(s, 8, 64);
            s += __shfl_xor(s, 16, 64);
            if (tc2 == 0) {
                int p = pbase + pp0 + jp;
                if (p < 127) out[g*127 + p] = s + bd2v;
            }
        }
    }
}

extern "C" void kernel_launch(void* const* d_in, const int* in_sizes, int n_in,
                              void* d_out, int out_size, void* d_ws, size_t ws_size,
                              hipStream_t stream) {
    const float* x   = (const float*)d_in[0];
    const int*   ei  = (const int*)d_in[1];   // [2][E] int32
    const float* W1  = (const float*)d_in[4];
    const float* b1  = (const float*)d_in[5];
    const float* W2  = (const float*)d_in[6];
    const float* b2  = (const float*)d_in[7];
    const float* W3  = (const float*)d_in[8];
    const float* b3  = (const float*)d_in[9];
    const float* W4  = (const float*)d_in[10];
    const float* b4  = (const float*)d_in[11];
    const float* W5  = (const float*)d_in[12];
    const float* b5  = (const float*)d_in[13];
    const float* Wd1 = (const float*)d_in[14];
    const float* bd1 = (const float*)d_in[15];
    const float* Wd2 = (const float*)d_in[16];
    const float* bd2 = (const float*)d_in[17];
    float* out = (float*)d_out;

    float* ws  = (float*)d_ws;
    float* h0  = ws;                        // 2^21 floats
    float* h1  = ws + 2097152;              // 2^21 floats
    float* Tt  = ws + 4194304;              // 2^20 floats
    float* Wc  = ws + 5242880;              // 8448 floats
    float* Wd1t = ws + 5251328;             // 8192 floats
    int*   deg  = (int*)(ws + 5259520);
    int*   offs = deg + NN;
    int*   cur  = offs + NN;
    int*   csr  = cur + NN;                 // EE ints

    const int* src = ei;
    const int* dst = ei + EE;

    k_prep<<<32, 256, 0, stream>>>(W2, b2, W3, b3, W4, b4, Wc);
    k_twd1<<<1, 256, 0, stream>>>(Wd1, Wd1t);
    k_init<<<NN/4, 256, 0, stream>>>(x, W1, b1, h0);

    hipMemsetAsync(deg, 0, NN * sizeof(int), stream);
    k_hist<<<EE/256, 256, 0, stream>>>(dst, deg);
    k_scan<<<1, 256, 0, stream>>>(deg, offs, cur);
    k_fill<<<EE/256, 256, 0, stream>>>(src, dst, cur, csr);

    float* hc = h0; float* hn = h1;
    for (int l = 0; l < 3; ++l) {
        // gather writes messages into hn; k_gemm consumes them in-place and
        // overwrites hn with the updated node features (block-local alias,
        // safe: each block stages its own tile before writing it).
        k_gather<<<NN/4, 256, 0, stream>>>(hc, offs, deg, csr, hn);
        k_gemm<<<NN/32, 256, 0, stream>>>(Wc, hn, hc);
        float* tmp = hc; hc = hn; hn = tmp;
    }

    k_tmat<<<256, 256, 0, stream>>>(hc, W5, Tt);
    k_readout<<<512, 256, 0, stream>>>(hc, Tt, b5, Wd1t, bd1, Wd2, bd2, out);
}

// Round 5
// 306.675 us; speedup vs baseline: 2.5725x; 1.0308x over previous
//
#include <hip/hip_runtime.h>
#include <hip/hip_bf16.h>

#define NN 32768
#define EE 524288
#define GG 256
#define PP 128

// ---------------------------------------------------------------------------
// k_weights: blocks 0..31 fold W2/W3/W4/biases into Wc[kk][o] (128x64) + c;
// block 32 transposes Wd1[128][64] -> Wd1t[64][128].
// ---------------------------------------------------------------------------
__global__ void k_weights(const float* __restrict__ W2, const float* __restrict__ b2,
                          const float* __restrict__ W3, const float* __restrict__ b3,
                          const float* __restrict__ W4, const float* __restrict__ b4,
                          const float* __restrict__ Wd1, float* __restrict__ Wc,
                          float* __restrict__ Wd1t) {
    __shared__ float tile[128 * 65];
    int t = threadIdx.x;
    if (blockIdx.x == 32) {          // Wd1 transpose
        for (int idx = t; idx < 8192; idx += 256) {
            int q = idx >> 6, o = idx & 63;
            tile[q*65 + o] = Wd1[idx];
        }
        __syncthreads();
        for (int idx = t; idx < 8192; idx += 256) {
            int o = idx >> 7, q = idx & 127;
            Wd1t[idx] = tile[q*65 + o];
        }
        return;
    }
    int idx = blockIdx.x * 256 + t;  // 0..8191
    int kk = idx >> 6, o = idx & 63;
    float a = 0.f;
    if (kk < 64) {
        for (int j = 0; j < 64; ++j) a += W4[o*128 + j] * W3[j*64 + kk];
    } else {
        int k2 = kk - 64;
        for (int j = 0; j < 64; ++j) a += W4[o*128 + 64 + j] * W2[j*64 + k2];
    }
    Wc[kk*64 + o] = a;
    if (idx < 64) {
        float c = b4[idx];
        for (int j = 0; j < 64; ++j)
            c += W4[idx*128 + j]*b3[j] + W4[idx*128 + 64 + j]*b2[j];
        Wc[8192 + idx] = c;
    }
}

// ---------------------------------------------------------------------------
// k_init: h = normalize(relu(x @ W1.T + b1)). One wave per node, lane = out.
// First 128 blocks also zero deg[] (replaces a separate memset dispatch;
// stream order puts this before k_hist).
// ---------------------------------------------------------------------------
__global__ void k_init(const float* __restrict__ x, const float* __restrict__ W1,
                       const float* __restrict__ b1, float* __restrict__ h,
                       int* __restrict__ deg) {
    if (blockIdx.x < 128) deg[blockIdx.x * 256 + threadIdx.x] = 0;
    int node = (blockIdx.x * blockDim.x + threadIdx.x) >> 6;
    int lane = threadIdx.x & 63;
    if (node >= NN) return;
    float acc = b1[lane];
    #pragma unroll
    for (int j = 0; j < 8; ++j)
        acc += x[node*8 + j] * W1[lane*8 + j];
    acc = fmaxf(acc, 0.f);
    float ss = acc * acc;
    #pragma unroll
    for (int m = 1; m < 64; m <<= 1) ss += __shfl_xor(ss, m, 64);
    h[node*64 + lane] = acc / sqrtf(ss);
}

// ---------------------------------------------------------------------------
// CSR build: int4 histogram, 1024-thread register scan (+ sentinel), int4 fill.
// ---------------------------------------------------------------------------
__global__ void k_hist(const int* __restrict__ dst, int* __restrict__ deg) {
    int i = blockIdx.x * blockDim.x + threadIdx.x;   // EE/4 threads
    int4 d = ((const int4*)dst)[i];
    atomicAdd(&deg[d.x], 1);
    atomicAdd(&deg[d.y], 1);
    atomicAdd(&deg[d.z], 1);
    atomicAdd(&deg[d.w], 1);
}

__global__ void __launch_bounds__(1024) k_scan(
        const int* __restrict__ deg, int* __restrict__ offs,
        int* __restrict__ cur) {
    __shared__ int part[1024];
    int t = threadIdx.x;
    int4 v[8];
    int base4 = t * 8;                  // int4 index; 32 ints per thread
    int s = 0;
    #pragma unroll
    for (int j = 0; j < 8; ++j) {
        v[j] = ((const int4*)deg)[base4 + j];
        s += v[j].x + v[j].y + v[j].z + v[j].w;
    }
    part[t] = s;
    __syncthreads();
    for (int off = 1; off < 1024; off <<= 1) {
        int tmp = (t >= off) ? part[t - off] : 0;
        __syncthreads();
        part[t] += tmp;
        __syncthreads();
    }
    int run = part[t] - s;
    #pragma unroll
    for (int j = 0; j < 8; ++j) {
        int4 o;
        o.x = run; run += v[j].x;
        o.y = run; run += v[j].y;
        o.z = run; run += v[j].z;
        o.w = run; run += v[j].w;
        ((int4*)offs)[base4 + j] = o;
        ((int4*)cur)[base4 + j]  = o;
    }
    if (t == 1023) offs[NN] = part[1023];   // sentinel (== EE)
}

__global__ void k_fill(const int* __restrict__ src, const int* __restrict__ dst,
                       int* __restrict__ cur, int* __restrict__ csr) {
    int i = blockIdx.x * blockDim.x + threadIdx.x;   // EE/4 threads
    int4 s4 = ((const int4*)src)[i];
    int4 d4 = ((const int4*)dst)[i];
    csr[atomicAdd(&cur[d4.x], 1)] = s4.x;
    csr[atomicAdd(&cur[d4.y], 1)] = s4.y;
    csr[atomicAdd(&cur[d4.z], 1)] = s4.z;
    csr[atomicAdd(&cur[d4.w], 1)] = s4.w;
}

// ---------------------------------------------------------------------------
// k_gather: segment_sum via CSR. ONE NODE PER WAVE (32768 independent waves,
// no LDS, no barriers). Lane split: fg4=(lane&15)*4 features (float4),
// es=lane>>4 edge slot. Branchless 16-edge rounds; tail via clamp + 0-weight.
// Cross-slot reduce: shfl_xor 16/32. Degree from offs sentinel (no deg load).
// ---------------------------------------------------------------------------
__global__ void __launch_bounds__(256) k_gather(
        const float* __restrict__ h, const int* __restrict__ offs,
        const int* __restrict__ csr, float* __restrict__ m) {
    int node = (blockIdx.x * blockDim.x + threadIdx.x) >> 6;
    int lane = threadIdx.x & 63;
    int fg4 = (lane & 15) * 4, es = lane >> 4;
    int st = offs[node], de = offs[node + 1] - st;
    float4 acc = make_float4(0.f, 0.f, 0.f, 0.f);
    for (int e = es; e < de; e += 16) {
        int a0 = st + e;                       // e < de: always valid
        int a1 = min(st + e + 4,  EE - 1);
        int a2 = min(st + e + 8,  EE - 1);
        int a3 = min(st + e + 12, EE - 1);
        int i0 = csr[a0], i1 = csr[a1], i2 = csr[a2], i3 = csr[a3];
        float w1 = (e + 4  < de) ? 1.f : 0.f;
        float w2 = (e + 8  < de) ? 1.f : 0.f;
        float w3 = (e + 12 < de) ? 1.f : 0.f;
        float4 v0 = *(const float4*)&h[(long)i0*64 + fg4];
        float4 v1 = *(const float4*)&h[(long)i1*64 + fg4];
        float4 v2 = *(const float4*)&h[(long)i2*64 + fg4];
        float4 v3 = *(const float4*)&h[(long)i3*64 + fg4];
        acc.x += v0.x + w1*v1.x + w2*v2.x + w3*v3.x;
        acc.y += v0.y + w1*v1.y + w2*v2.y + w3*v3.y;
        acc.z += v0.z + w1*v1.z + w2*v2.z + w3*v3.z;
        acc.w += v0.w + w1*v1.w + w2*v2.w + w3*v3.w;
    }
    acc.x += __shfl_xor(acc.x, 16, 64); acc.y += __shfl_xor(acc.y, 16, 64);
    acc.z += __shfl_xor(acc.z, 16, 64); acc.w += __shfl_xor(acc.w, 16, 64);
    acc.x += __shfl_xor(acc.x, 32, 64); acc.y += __shfl_xor(acc.y, 32, 64);
    acc.z += __shfl_xor(acc.z, 32, 64); acc.w += __shfl_xor(acc.w, 32, 64);
    if (es == 0) *(float4*)&m[(long)node*64 + fg4] = acc;
}

// ---------------------------------------------------------------------------
// k_gemm: hn[n][o] = normalize(relu(sum_kk X[n][kk]*Wc[kk][o] + c[o])),
// X = [m | h]. mio holds m on entry and receives hn (block-local alias:
// each block stages its own 32-row tile into LDS before overwriting it).
// Thread tile 2 nodes x 4 outs, float4 LDS reads both operands.
// ---------------------------------------------------------------------------
__global__ void __launch_bounds__(256) k_gemm(
        const float* __restrict__ Wc, float* mio,
        const float* __restrict__ hcur) {
    __shared__ float Wl[8192];       // [kk][o], stride 64
    __shared__ float Xl[32 * 132];   // [n][kk], stride 132
    int t = threadIdx.x;
    int nbase = blockIdx.x * 32;

    for (int i = t * 4; i < 8192; i += 1024)
        *(float4*)&Wl[i] = *(const float4*)&Wc[i];
    for (int idx = t; idx < 512; idx += 256) {
        int n = idx >> 4, c = (idx & 15) * 4;
        *(float4*)&Xl[n*132 + c]      = *(const float4*)&mio[(long)(nbase+n)*64 + c];
        *(float4*)&Xl[n*132 + 64 + c] = *(const float4*)&hcur[(long)(nbase+n)*64 + c];
    }
    __syncthreads();

    int tc = t & 15, tr = t >> 4;
    int o0 = tc * 4, n0 = tr * 2;
    float4 c4 = *(const float4*)&Wc[8192 + o0];
    float acc0[4] = {0.f,0.f,0.f,0.f};
    float acc1[4] = {0.f,0.f,0.f,0.f};
    #pragma unroll 4
    for (int kk = 0; kk < 128; kk += 4) {
        float4 w0 = *(float4*)&Wl[(kk+0)*64 + o0];
        float4 w1 = *(float4*)&Wl[(kk+1)*64 + o0];
        float4 w2 = *(float4*)&Wl[(kk+2)*64 + o0];
        float4 w3 = *(float4*)&Wl[(kk+3)*64 + o0];
        float4 x0 = *(float4*)&Xl[(n0+0)*132 + kk];
        float4 x1 = *(float4*)&Xl[(n0+1)*132 + kk];
        acc0[0] += x0.x*w0.x + x0.y*w1.x + x0.z*w2.x + x0.w*w3.x;
        acc0[1] += x0.x*w0.y + x0.y*w1.y + x0.z*w2.y + x0.w*w3.y;
        acc0[2] += x0.x*w0.z + x0.y*w1.z + x0.z*w2.z + x0.w*w3.z;
        acc0[3] += x0.x*w0.w + x0.y*w1.w + x0.z*w2.w + x0.w*w3.w;
        acc1[0] += x1.x*w0.x + x1.y*w1.x + x1.z*w2.x + x1.w*w3.x;
        acc1[1] += x1.x*w0.y + x1.y*w1.y + x1.z*w2.y + x1.w*w3.y;
        acc1[2] += x1.x*w0.z + x1.y*w1.z + x1.z*w2.z + x1.w*w3.z;
        acc1[3] += x1.x*w0.w + x1.y*w1.w + x1.z*w2.w + x1.w*w3.w;
    }

    #pragma unroll
    for (int jn = 0; jn < 2; ++jn) {
        float* a = jn ? acc1 : acc0;
        float v0 = fmaxf(a[0] + c4.x, 0.f);
        float v1 = fmaxf(a[1] + c4.y, 0.f);
        float v2 = fmaxf(a[2] + c4.z, 0.f);
        float v3 = fmaxf(a[3] + c4.w, 0.f);
        float ss = v0*v0 + v1*v1 + v2*v2 + v3*v3;
        ss += __shfl_xor(ss, 1, 64);
        ss += __shfl_xor(ss, 2, 64);
        ss += __shfl_xor(ss, 4, 64);
        ss += __shfl_xor(ss, 8, 64);
        float r = 1.0f / sqrtf(ss);
        float4 outv = make_float4(v0*r, v1*r, v2*r, v3*r);
        *(float4*)&mio[(long)(nbase + n0 + jn)*64 + o0] = outv;
    }
}

// ---------------------------------------------------------------------------
// k_tmat: Tt[g][i*64+o] = sum_j W5[o][i*64+j] * last[g][j].
// 256 blocks = 16 consecutive rows r = i*64+o each; thread = graph.
// ---------------------------------------------------------------------------
__global__ void __launch_bounds__(256) k_tmat(
        const float* __restrict__ h, const float* __restrict__ W5,
        float* __restrict__ Tt) {
    __shared__ float lastL[256 * 65];   // 66.6 KB
    __shared__ float wL[64 * 16];       // [j][rr]
    __shared__ float tr[16 * 257];      // [rr][g]
    int t = threadIdx.x;
    int rb = blockIdx.x * 16;
    int i = rb >> 6, obase = rb & 63;

    for (int idx4 = t; idx4 < 4096; idx4 += 256) {
        int g = idx4 >> 4, c = (idx4 & 15) * 4;
        *(float4*)&lastL[g*65 + c] =
            *(const float4*)&h[((long)g*128 + 127)*64 + c];
    }
    {   // stage W5 slice, transposed to [j][rr]
        int rr = t & 15, j0 = (t >> 4) * 4;
        float4 w = *(const float4*)&W5[(long)(obase + rr)*4096 + i*64 + j0];
        wL[(j0+0)*16 + rr] = w.x;
        wL[(j0+1)*16 + rr] = w.y;
        wL[(j0+2)*16 + rr] = w.z;
        wL[(j0+3)*16 + rr] = w.w;
    }
    __syncthreads();

    int g = t;
    float acc[16] = {};
    for (int j = 0; j < 64; ++j) {
        float lv = lastL[g*65 + j];
        #pragma unroll
        for (int r4 = 0; r4 < 4; ++r4) {
            float4 wv = *(float4*)&wL[j*16 + r4*4];
            acc[r4*4+0] += wv.x * lv;
            acc[r4*4+1] += wv.y * lv;
            acc[r4*4+2] += wv.z * lv;
            acc[r4*4+3] += wv.w * lv;
        }
    }
    #pragma unroll
    for (int rr = 0; rr < 16; ++rr) tr[rr*257 + g] = acc[rr];
    __syncthreads();
    for (int it = 0; it < 4; ++it) {
        int idx = t + it*256;
        int g2 = idx >> 2, c4 = idx & 3;
        float4 v = make_float4(tr[(c4*4+0)*257 + g2], tr[(c4*4+1)*257 + g2],
                               tr[(c4*4+2)*257 + g2], tr[(c4*4+3)*257 + g2]);
        *(float4*)&Tt[(long)g2*4096 + rb + c4*4] = v;
    }
}

// ---------------------------------------------------------------------------
// k_readout: per-graph GEMM chain, 2 blocks/graph, 2 p-tiles of 32 each.
// ---------------------------------------------------------------------------
__global__ void __launch_bounds__(256) k_readout(
        const float* __restrict__ h, const float* __restrict__ Tt,
        const float* __restrict__ b5, const float* __restrict__ Wd1t,
        const float* __restrict__ bd1, const float* __restrict__ Wd2,
        const float* __restrict__ bd2, float* __restrict__ out) {
    __shared__ float Tl[4096];       // [i][o], stride 64
    __shared__ float W1t[8192];      // [o][q], stride 128
    __shared__ float OY[32 * 68];    // [p][i] then [p][o], stride 68
    int t = threadIdx.x;
    int g = blockIdx.x >> 1, half = blockIdx.x & 1;

    for (int i = t * 4; i < 4096; i += 1024)
        *(float4*)&Tl[i] = *(const float4*)&Tt[(long)g*4096 + i];
    for (int i = t * 4; i < 8192; i += 1024)
        *(float4*)&W1t[i] = *(const float4*)&Wd1t[i];

    int tc = t & 15, tr = t >> 4;      // GEMM1 map
    int o0 = tc * 4, p0 = tr * 2;
    int tc2 = t & 31, tr2 = t >> 5;    // GEMM2 map
    int q0 = tc2 * 4, pp0 = tr2 * 4;
    float4 b5_4  = *(const float4*)&b5[o0];
    float4 bd1_4 = *(const float4*)&bd1[q0];
    float4 wd2_4 = *(const float4*)&Wd2[q0];
    float bd2v = bd2[0];

    for (int pt = half*2; pt < half*2 + 2; ++pt) {
        int pbase = pt * 32;
        __syncthreads();
        for (int idx = t; idx < 512; idx += 256) {
            int p = idx >> 4, c = (idx & 15) * 4;
            *(float4*)&OY[p*68 + c] =
                *(const float4*)&h[((long)g*128 + pbase + p)*64 + c];
        }
        __syncthreads();

        // GEMM1
        float a10[4] = {0.f,0.f,0.f,0.f};
        float a11[4] = {0.f,0.f,0.f,0.f};
        #pragma unroll 4
        for (int i = 0; i < 64; i += 4) {
            float4 w0 = *(float4*)&Tl[(i+0)*64 + o0];
            float4 w1 = *(float4*)&Tl[(i+1)*64 + o0];
            float4 w2 = *(float4*)&Tl[(i+2)*64 + o0];
            float4 w3 = *(float4*)&Tl[(i+3)*64 + o0];
            float4 x0 = *(float4*)&OY[(p0+0)*68 + i];
            float4 x1 = *(float4*)&OY[(p0+1)*68 + i];
            a10[0] += x0.x*w0.x + x0.y*w1.x + x0.z*w2.x + x0.w*w3.x;
            a10[1] += x0.x*w0.y + x0.y*w1.y + x0.z*w2.y + x0.w*w3.y;
            a10[2] += x0.x*w0.z + x0.y*w1.z + x0.z*w2.z + x0.w*w3.z;
            a10[3] += x0.x*w0.w + x0.y*w1.w + x0.z*w2.w + x0.w*w3.w;
            a11[0] += x1.x*w0.x + x1.y*w1.x + x1.z*w2.x + x1.w*w3.x;
            a11[1] += x1.x*w0.y + x1.y*w1.y + x1.z*w2.y + x1.w*w3.y;
            a11[2] += x1.x*w0.z + x1.y*w1.z + x1.z*w2.z + x1.w*w3.z;
            a11[3] += x1.x*w0.w + x1.y*w1.w + x1.z*w2.w + x1.w*w3.w;
        }
        __syncthreads();

        float4 y0 = make_float4(a10[0]+b5_4.x, a10[1]+b5_4.y, a10[2]+b5_4.z, a10[3]+b5_4.w);
        float4 y1 = make_float4(a11[0]+b5_4.x, a11[1]+b5_4.y, a11[2]+b5_4.z, a11[3]+b5_4.w);
        *(float4*)&OY[(p0+0)*68 + o0] = y0;
        *(float4*)&OY[(p0+1)*68 + o0] = y1;
        __syncthreads();

        // GEMM2
        float a2[4][4] = {};
        #pragma unroll 4
        for (int o = 0; o < 64; o += 4) {
            float4 w0 = *(float4*)&W1t[(o+0)*128 + q0];
            float4 w1 = *(float4*)&W1t[(o+1)*128 + q0];
            float4 w2 = *(float4*)&W1t[(o+2)*128 + q0];
            float4 w3 = *(float4*)&W1t[(o+3)*128 + q0];
            #pragma unroll
            for (int jp = 0; jp < 4; ++jp) {
                float4 yv = *(float4*)&OY[(pp0+jp)*68 + o];
                a2[jp][0] += yv.x*w0.x + yv.y*w1.x + yv.z*w2.x + yv.w*w3.x;
                a2[jp][1] += yv.x*w0.y + yv.y*w1.y + yv.z*w2.y + yv.w*w3.y;
                a2[jp][2] += yv.x*w0.z + yv.y*w1.z + yv.z*w2.z + yv.w*w3.z;
                a2[jp][3] += yv.x*w0.w + yv.y*w1.w + yv.z*w2.w + yv.w*w3.w;
            }
        }

        #pragma unroll
        for (int jp = 0; jp < 4; ++jp) {
            float s = wd2_4.x * fmaxf(a2[jp][0] + bd1_4.x, 0.f)
                    + wd2_4.y * fmaxf(a2[jp][1] + bd1_4.y, 0.f)
                    + wd2_4.z * fmaxf(a2[jp][2] + bd1_4.z, 0.f)
                    + wd2_4.w * fmaxf(a2[jp][3] + bd1_4.w, 0.f);
            s += __shfl_xor(s, 1, 64);
            s += __shfl_xor(s, 2, 64);
            s += __shfl_xor(s, 4, 64);
            s += __shfl_xor(s, 8, 64);
            s += __shfl_xor(s, 16, 64);
            if (tc2 == 0) {
                int p = pbase + pp0 + jp;
                if (p < 127) out[g*127 + p] = s + bd2v;
            }
        }
    }
}

extern "C" void kernel_launch(void* const* d_in, const int* in_sizes, int n_in,
                              void* d_out, int out_size, void* d_ws, size_t ws_size,
                              hipStream_t stream) {
    const float* x   = (const float*)d_in[0];
    const int*   ei  = (const int*)d_in[1];   // [2][E] int32
    const float* W1  = (const float*)d_in[4];
    const float* b1  = (const float*)d_in[5];
    const float* W2  = (const float*)d_in[6];
    const float* b2  = (const float*)d_in[7];
    const float* W3  = (const float*)d_in[8];
    const float* b3  = (const float*)d_in[9];
    const float* W4  = (const float*)d_in[10];
    const float* b4  = (const float*)d_in[11];
    const float* W5  = (const float*)d_in[12];
    const float* b5  = (const float*)d_in[13];
    const float* Wd1 = (const float*)d_in[14];
    const float* bd1 = (const float*)d_in[15];
    const float* Wd2 = (const float*)d_in[16];
    const float* bd2 = (const float*)d_in[17];
    float* out = (float*)d_out;

    float* ws  = (float*)d_ws;
    float* h0   = ws;                        // 2^21 floats
    float* h1   = ws + 2097152;              // 2^21 floats
    float* Tt   = ws + 4194304;              // 2^20 floats
    float* Wc   = ws + 5242880;              // 8448 floats
    float* Wd1t = ws + 5251328;              // 8192 floats
    int*   deg  = (int*)(ws + 5259520);      // NN
    int*   offs = deg + NN;                  // NN+1 (+pad to 16)
    int*   cur  = offs + NN + 16;            // NN
    int*   csr  = cur + NN;                  // EE

    const int* src = ei;
    const int* dst = ei + EE;

    k_weights<<<33, 256, 0, stream>>>(W2, b2, W3, b3, W4, b4, Wd1, Wc, Wd1t);
    k_init<<<NN/4, 256, 0, stream>>>(x, W1, b1, h0, deg);

    k_hist<<<EE/1024, 256, 0, stream>>>(dst, deg);
    k_scan<<<1, 1024, 0, stream>>>(deg, offs, cur);
    k_fill<<<EE/1024, 256, 0, stream>>>(src, dst, cur, csr);

    float* hc = h0; float* hn = h1;
    for (int l = 0; l < 3; ++l) {
        // gather writes messages into hn; k_gemm consumes them in-place and
        // overwrites hn with the updated node features (block-local alias).
        k_gather<<<NN/4, 256, 0, stream>>>(hc, offs, csr, hn);
        k_gemm<<<NN/32, 256, 0, stream>>>(Wc, hn, hc);
        float* tmp = hc; hc = hn; hn = tmp;
    }

    k_tmat<<<256, 256, 0, stream>>>(hc, W5, Tt);
    k_readout<<<512, 256, 0, stream>>>(hc, Tt, b5, Wd1t, bd1, Wd2, bd2, out);
}